// Round 9
// baseline (152.256 us; speedup 1.0000x reference)
//
#include <hip/hip_runtime.h>
#include <stdint.h>

#define B_ 4
#define C_ 64
#define H_ 96
#define W_ 96
#define HP_ 48
#define WP_ 48
#define N_ (H_*W_)      // 9216
#define M_ (HP_*WP_)    // 2304
#define KD_ 64
#define OD_ 64
#define BN_EPS 1e-5f
#define LOG2E 1.4426950408889634f
#define SHIFT2 28.853900817779268f   // 20 * LOG2E
#define QT_ 48                        // q-tile: 768 blocks = exactly 3/CU
#define QI_ (QT_/16)                  // 3 q-frags per block
#define QB_ (N_/QT_)                  // 192 q-tiles per batch
#define NT_ (M_/64)                   // 36 m-tiles (even — 2x unroll relies on it)

typedef __bf16 bf16_t;
typedef bf16_t bf16x8 __attribute__((ext_vector_type(8)));
typedef bf16_t bf16x4 __attribute__((ext_vector_type(4)));
typedef float f32x4 __attribute__((ext_vector_type(4)));
typedef short short4v __attribute__((ext_vector_type(4)));

static __device__ __forceinline__ unsigned short f2bf(float f) {
    unsigned int u = __builtin_bit_cast(unsigned int, f);
    u += 0x7fffu + ((u >> 16) & 1u);
    return (unsigned short)(u >> 16);
}

static __device__ __forceinline__ f32x4 mfma16_bf16(short4v a, short4v b, f32x4 c) {
#if __has_builtin(__builtin_amdgcn_mfma_f32_16x16x16bf16_1k)
    return __builtin_amdgcn_mfma_f32_16x16x16bf16_1k(a, b, c, 0, 0, 0);
#else
    return c;  // host pass only — never executed on device
#endif
}

// async global->LDS DMA, 16B per lane. LDS dest must be linear.
static __device__ __forceinline__ void gl_lds16(const unsigned short* g, unsigned short* l) {
#if __has_builtin(__builtin_amdgcn_global_load_lds)
    __builtin_amdgcn_global_load_lds(
        (const __attribute__((address_space(1))) unsigned int*)(const void*)g,
        (__attribute__((address_space(3))) unsigned int*)(void*)l, 16, 0, 0);
#endif
}

static __device__ __forceinline__ void setprio1() {
#if __has_builtin(__builtin_amdgcn_s_setprio)
    __builtin_amdgcn_s_setprio(1);
#endif
}
static __device__ __forceinline__ void setprio0() {
#if __has_builtin(__builtin_amdgcn_s_setprio)
    __builtin_amdgcn_s_setprio(0);
#endif
}
static __device__ __forceinline__ void schedbar0() {
#if __has_builtin(__builtin_amdgcn_sched_barrier)
    __builtin_amdgcn_sched_barrier(0);
#endif
}
static __device__ __forceinline__ void rawbar() {
#if __has_builtin(__builtin_amdgcn_s_barrier)
    __builtin_amdgcn_s_barrier();
#else
    __syncthreads();
#endif
}

// ---------------- Kernel 1: fused pool(x,c2) + key conv + edge attention ----------------
__global__ __launch_bounds__(256) void prep_kernel(
    const float* __restrict__ x, const float* __restrict__ c2,
    const float* __restrict__ wq, const float* __restrict__ bq,
    const float* __restrict__ w1, const float* __restrict__ bnw, const float* __restrict__ bnb,
    const float* __restrict__ bnm, const float* __restrict__ bnv,
    const float* __restrict__ w2, const float* __restrict__ b2,
    unsigned short* __restrict__ kb, unsigned short* __restrict__ vb, float* __restrict__ ea) {

    __shared__ float lw1[OD_*2*C_];
    __shared__ float lwq[KD_*C_];
    __shared__ float xs[C_*33];
    __shared__ float c2s[C_*33];
    __shared__ float red[8][32];

    int tid = threadIdx.x;
    int b = blockIdx.x / 72;
    int m0 = (blockIdx.x % 72) * 32;

    for (int i = tid; i < OD_*2*C_; i += 256) lw1[i] = w1[i];
    for (int i = tid; i < KD_*C_; i += 256) lwq[i] = wq[i];
    for (int j = tid; j < 2048; j += 256) {
        int c = j >> 5, p = j & 31;
        int m = m0 + p;
        int hp = m / WP_, wp = m % WP_;
        size_t base = ((size_t)(b*C_ + c)*H_ + 2*hp)*W_ + 2*wp;
        const float* px = x + base;
        float mx = fmaxf(fmaxf(px[0], px[1]), fmaxf(px[W_], px[W_+1]));
        xs[c*33 + p] = mx;
        vb[(size_t)(b*C_ + c)*M_ + m] = f2bf(mx);
        const float* pc = c2 + base;
        c2s[c*33 + p] = fmaxf(fmaxf(pc[0], pc[1]), fmaxf(pc[W_], pc[W_+1]));
    }
    __syncthreads();

    int ml = tid & 31, oz = tid >> 5;
    int m = m0 + ml;

    float h[8] = {0,0,0,0,0,0,0,0};
    for (int c = 0; c < C_; c += 4) {
        float x0 = xs[c*33+ml], x1 = xs[(c+1)*33+ml], x2 = xs[(c+2)*33+ml], x3 = xs[(c+3)*33+ml];
        #pragma unroll
        for (int oi = 0; oi < 8; oi++) {
            const float4 wv = *(const float4*)&lwq[(oz*8 + oi)*C_ + c];
            h[oi] = fmaf(wv.x, x0, fmaf(wv.y, x1, fmaf(wv.z, x2, fmaf(wv.w, x3, h[oi]))));
        }
    }
    unsigned short tmp[8];
    #pragma unroll
    for (int oi = 0; oi < 8; oi++) tmp[oi] = f2bf(h[oi] + bq[oz*8 + oi]);
    *(uint4*)&kb[((size_t)b*M_ + m)*KD_ + oz*8] = *(const uint4*)tmp;

    float g[8] = {0,0,0,0,0,0,0,0};
    for (int c = 0; c < 2*C_; c += 4) {
        const float* srcb = (c < C_) ? &c2s[c*33] : &xs[(c - C_)*33];
        float x0 = srcb[ml], x1 = srcb[33+ml], x2 = srcb[66+ml], x3 = srcb[99+ml];
        #pragma unroll
        for (int oi = 0; oi < 8; oi++) {
            const float4 wv = *(const float4*)&lw1[(oz*8 + oi)*(2*C_) + c];
            g[oi] = fmaf(wv.x, x0, fmaf(wv.y, x1, fmaf(wv.z, x2, fmaf(wv.w, x3, g[oi]))));
        }
    }
    float z = 0.f;
    #pragma unroll
    for (int oi = 0; oi < 8; oi++) {
        int o = oz*8 + oi;
        float sc = bnw[o] * rsqrtf(bnv[o] + BN_EPS);
        float t = (g[oi] - bnm[o]) * sc + bnb[o];
        z += w2[o] * fmaxf(t, 0.f);
    }
    red[oz][ml] = z;
    __syncthreads();
    if (oz == 0) {
        float s = b2[0];
        #pragma unroll
        for (int i = 0; i < 8; i++) s += red[i][ml];
        ea[(size_t)b*M_ + m] = LOG2E / (1.f + __builtin_amdgcn_exp2f(-s * LOG2E));
    }
}

// ---------------- Kernel 2: flash attention with fused q-conv prologue ----------------
// R9: prologue data path rebuilt. R8's q-conv did 128 scattered global loads
// per thread (stride-36KB, latency-serialized -> 6.6us). Now: x-slice
// (48n x 64c fp32 = 12KB) staged COALESCED into LDS [c][48n] (write: lanes
// scan n -> conflict-free; read: lanes scan n -> conflict-free; dup lanes
// broadcast), conv runs fp32 FMA from LDS (identical arithmetic, absmax
// unchanged). w_q at smem+13056 (buf0/buf1 overlay), q-bf16 scratch in the
// ea region (consumed into regs before ea staging overwrites it).
// Main loop unchanged from R6/R8: reg-level 1-deep frag pipeline, counted
// vmcnt, one barrier/step, setprio, ones-MFMA denominator.
__global__ __launch_bounds__(256, 3) void attn_kernel(
    const float* __restrict__ wq, const float* __restrict__ bq,
    const unsigned short* __restrict__ kb, const unsigned short* __restrict__ vb,
    const float* __restrict__ ea, const float* __restrict__ x,
    const float* __restrict__ gamma_p, float* __restrict__ out) {

    // dbuf: [k 8192 | v 8192] x2 = 32768 B, ea 9216 B -> 41984 B
    // prologue overlay: lds_x 12288 @0, w_q 16384 @13056 (ends 29440<=32768),
    //                   qlds 6144 @32768 (ea region, freed before ea staging)
    // epilogue overlay: o_red 2*48*68*4=26112 + l_red 768 = 26880 B (fits)
    __shared__ __align__(16) char smem[41984];

    int tid = threadIdx.x;
    int wave = tid >> 6, lane = tid & 63, quad = lane >> 4, l16 = lane & 15;
    int blk = blockIdx.x;
    int b = (blk & 7) >> 1;                       // batch pinned to XCD pair
    int n_base = ((blk & 1) * (QB_/2) + (blk >> 3)) * QT_;
    int xsw = l16 & 7;

    // ---- fused q-conv (LDS-staged inputs) ----
    float* lds_x = (float*)smem;                            // [64 c][48 n]
    float* lwq   = (float*)(smem + 13056);                  // [64 k][64 c]
    unsigned short* qlds = (unsigned short*)(smem + 32768); // [48 n][64 k] bf16 swz
    {
        const float* xb = x + (size_t)b*C_*N_ + n_base;
        #pragma unroll
        for (int i = 0; i < 3; i++) {
            int idx = tid + i*256;         // float4 index: c = idx/12, chunk = idx%12
            int c = idx / 12, ch = idx % 12;
            *(float4*)&lds_x[c*48 + ch*4] = *(const float4*)(xb + (size_t)c*N_ + ch*4);
        }
    }
    for (int i = tid; i < KD_*C_; i += 256) lwq[i] = wq[i];
    __syncthreads();
    {
        // pass A: n = tid&31 (rows 0..31), channels (tid>>5)*8..+7
        {
            int ml = tid & 31, oz = tid >> 5;
            float h[8] = {0,0,0,0,0,0,0,0};
            for (int c = 0; c < C_; c += 4) {
                float x0 = lds_x[c*48+ml],     x1 = lds_x[(c+1)*48+ml];
                float x2 = lds_x[(c+2)*48+ml], x3 = lds_x[(c+3)*48+ml];
                #pragma unroll
                for (int oi = 0; oi < 8; oi++) {
                    const float4 wv = *(const float4*)&lwq[(oz*8 + oi)*C_ + c];
                    h[oi] = fmaf(wv.x, x0, fmaf(wv.y, x1, fmaf(wv.z, x2, fmaf(wv.w, x3, h[oi]))));
                }
            }
            unsigned short tmp[8];
            #pragma unroll
            for (int oi = 0; oi < 8; oi++) tmp[oi] = f2bf(h[oi] + bq[oz*8 + oi]);
            *(uint4*)&qlds[ml*64 + ((oz ^ (ml & 7)) << 3)] = *(const uint4*)tmp;
        }
        // pass B: n = 32 + (tid&15), channels (tid>>4)*4..+3
        {
            int ml = tid & 15, kq = tid >> 4;
            int n_l = 32 + ml;
            float h[4] = {0,0,0,0};
            for (int c = 0; c < C_; c += 4) {
                float x0 = lds_x[c*48+n_l],     x1 = lds_x[(c+1)*48+n_l];
                float x2 = lds_x[(c+2)*48+n_l], x3 = lds_x[(c+3)*48+n_l];
                #pragma unroll
                for (int oi = 0; oi < 4; oi++) {
                    const float4 wv = *(const float4*)&lwq[(kq*4 + oi)*C_ + c];
                    h[oi] = fmaf(wv.x, x0, fmaf(wv.y, x1, fmaf(wv.z, x2, fmaf(wv.w, x3, h[oi]))));
                }
            }
            unsigned short tmp[4];
            #pragma unroll
            for (int oi = 0; oi < 4; oi++) tmp[oi] = f2bf(h[oi] + bq[kq*4 + oi]);
            *(uint2*)&qlds[n_l*64 + (((kq >> 1) ^ (n_l & 7)) << 3) + (kq & 1)*4] =
                *(const uint2*)tmp;
        }
    }
    __syncthreads();

    // Q B-frags from the swizzled LDS scratch: B[col=q=qi*16+l16][k=quad*8+j]
    bf16x8 qf[QI_][2];
    #pragma unroll
    for (int qi = 0; qi < QI_; qi++) {
        const unsigned short* qp = qlds + (qi*16 + l16)*64;
        qf[qi][0] = __builtin_bit_cast(bf16x8, *(const uint4*)(qp + ((quad     ^ xsw) << 3)));
        qf[qi][1] = __builtin_bit_cast(bf16x8, *(const uint4*)(qp + (((quad+4) ^ xsw) << 3)));
    }

    f32x4 o2[QI_][4]; // O^T partial: [qi][ct]
    f32x4 lacc[QI_];  // denominator partials via ones-MFMA
    #pragma unroll
    for (int qi = 0; qi < QI_; qi++) {
        lacc[qi] = (f32x4){0.f,0.f,0.f,0.f};
        #pragma unroll
        for (int ct = 0; ct < 4; ct++) o2[qi][ct] = (f32x4){0.f,0.f,0.f,0.f};
    }
    const short one_bf = (short)0x3F80;  // bf16 1.0
    short4v ones = (short4v){one_bf, one_bf, one_bf, one_bf};

    const unsigned short* kbB = kb + (size_t)b*M_*KD_;
    const unsigned short* vbB = vb + (size_t)b*C_*M_;
    const float* eaB = ea + (size_t)b*M_;

    int srow = tid >> 3;                       // 0..31
    int ksw  = ((tid & 7) ^ (srow & 7)) << 3;  // swizzled src offset (shorts)

    auto STAGE = [&](int mb, char* kd, char* vd) {
        unsigned short* kds = (unsigned short*)kd;
        unsigned short* vds = (unsigned short*)vd;
        gl_lds16(kbB + (size_t)(mb + srow)*KD_      + ksw, kds + tid*8);
        gl_lds16(kbB + (size_t)(mb + srow + 32)*KD_ + ksw, kds + 2048 + tid*8);
        gl_lds16(vbB + (size_t)srow*M_      + mb + ksw, vds + tid*8);
        gl_lds16(vbB + (size_t)(srow+32)*M_ + mb + ksw, vds + 2048 + tid*8);
    };

    // ---- ea -> LDS; then stage tiles 0+1 (frags already in regs, sync'd) ----
    {
        const f32x4* eaV = (const f32x4*)eaB;
        f32x4* eaL = (f32x4*)(smem + 32768);
        for (int i = tid; i < M_/4; i += 256) eaL[i] = eaV[i];
    }
    asm volatile("s_waitcnt lgkmcnt(0)" ::: "memory"); // qf reads + ea ds_writes done
    __syncthreads();                                   // all waves done with qlds/w_q
    STAGE(0,  smem,          smem + 8192);
    STAGE(64, smem + 16384,  smem + 16384 + 8192);
    asm volatile("s_waitcnt vmcnt(4)" ::: "memory");   // tile0 DMA done (own wave)
    rawbar();                                          // => all waves' tile0 done
    asm volatile("" ::: "memory");

    const float* lds_ea = (const float*)(smem + 32768);
    int krow = wave*16 + l16;

    // frag double-buffer: two NAMED sets (constant field access only)
    struct FragSet { bf16x8 kf0, kf1; short4v va0, va1, va2, va3; f32x4 e4; };
    FragSet fA, fB;

    // read frag set for tile 0 into fA (from buf0)
    {
        unsigned short* kc = (unsigned short*)smem;
        unsigned short* vc = (unsigned short*)(smem + 8192);
        fA.e4  = *(const f32x4*)&lds_ea[0*64 + wave*16 + quad*4];
        fA.kf0 = __builtin_bit_cast(bf16x8, *(const uint4*)(kc + krow*KD_ + (((quad  ) ^ xsw) << 3)));
        fA.kf1 = __builtin_bit_cast(bf16x8, *(const uint4*)(kc + krow*KD_ + (((quad+4) ^ xsw) << 3)));
        fA.va0 = *(const short4v*)(vc + (0*16 + l16)*64 + (((wave*2 + (quad>>1)) ^ xsw) << 3) + (quad&1)*4);
        fA.va1 = *(const short4v*)(vc + (1*16 + l16)*64 + (((wave*2 + (quad>>1)) ^ xsw) << 3) + (quad&1)*4);
        fA.va2 = *(const short4v*)(vc + (2*16 + l16)*64 + (((wave*2 + (quad>>1)) ^ xsw) << 3) + (quad&1)*4);
        fA.va3 = *(const short4v*)(vc + (3*16 + l16)*64 + (((wave*2 + (quad>>1)) ^ xsw) << 3) + (quad&1)*4);
    }

// one pipeline step: compute tile T_ from CUR; prefetch T_+1 frags into NXT
#define ATTN_STEP(T_, CUR, NXT)                                                        \
    {                                                                                  \
        const int t_ = (T_);                                                           \
        if (t_ < NT_ - 1) {                                                            \
            asm volatile("s_waitcnt vmcnt(0)" ::: "memory");  /* tile t_+1 DMA done */ \
            schedbar0();                                                               \
            rawbar();                               /* acquire buf[(t_+1)&1], release buf[t_&1] */ \
            asm volatile("" ::: "memory");                                             \
            schedbar0();                                                               \
            if (t_ + 2 < NT_) {                                                        \
                char* nb = smem + (t_ & 1) * 16384;                                    \
                STAGE((t_ + 2) * 64, nb, nb + 8192);                                   \
            }                                                                          \
            unsigned short* kc_ = (unsigned short*)(smem + ((t_ + 1) & 1) * 16384);    \
            unsigned short* vc_ = (unsigned short*)(smem + ((t_ + 1) & 1) * 16384 + 8192); \
            NXT.e4  = *(const f32x4*)&lds_ea[(t_ + 1)*64 + wave*16 + quad*4];          \
            NXT.kf0 = __builtin_bit_cast(bf16x8, *(const uint4*)(kc_ + krow*KD_ + (((quad  ) ^ xsw) << 3))); \
            NXT.kf1 = __builtin_bit_cast(bf16x8, *(const uint4*)(kc_ + krow*KD_ + (((quad+4) ^ xsw) << 3))); \
            NXT.va0 = *(const short4v*)(vc_ + (0*16 + l16)*64 + (((wave*2 + (quad>>1)) ^ xsw) << 3) + (quad&1)*4); \
            NXT.va1 = *(const short4v*)(vc_ + (1*16 + l16)*64 + (((wave*2 + (quad>>1)) ^ xsw) << 3) + (quad&1)*4); \
            NXT.va2 = *(const short4v*)(vc_ + (2*16 + l16)*64 + (((wave*2 + (quad>>1)) ^ xsw) << 3) + (quad&1)*4); \
            NXT.va3 = *(const short4v*)(vc_ + (3*16 + l16)*64 + (((wave*2 + (quad>>1)) ^ xsw) << 3) + (quad&1)*4); \
            schedbar0();                                                               \
            asm volatile("s_waitcnt lgkmcnt(7)" ::: "memory"); /* CUR reads landed */  \
            schedbar0();                                                               \
        } else {                                                                       \
            schedbar0();                                                               \
            asm volatile("s_waitcnt lgkmcnt(0)" ::: "memory"); /* last frag set */     \
            schedbar0();                                                               \
        }                                                                              \
        /* ---- compute tile t_ from CUR (register-only) ---- */                       \
        f32x4 st[QI_];                                                                 \
        setprio1();                                                                    \
        _Pragma("unroll")                                                              \
        for (int qi = 0; qi < QI_; qi++) {                                             \
            f32x4 z = (f32x4){0.f,0.f,0.f,0.f};                                        \
            z = __builtin_amdgcn_mfma_f32_16x16x32_bf16(CUR.kf0, qf[qi][0], z, 0, 0, 0); \
            z = __builtin_amdgcn_mfma_f32_16x16x32_bf16(CUR.kf1, qf[qi][1], z, 0, 0, 0); \
            st[qi] = z;                                                                \
        }                                                                              \
        setprio0();                                                                    \
        short4v pk[QI_];                                                               \
        _Pragma("unroll")                                                              \
        for (int qi = 0; qi < QI_; qi++) {                                             \
            f32x4 p;                                                                   \
            p[0] = __builtin_amdgcn_exp2f(fmaf(st[qi][0], CUR.e4[0], -SHIFT2));        \
            p[1] = __builtin_amdgcn_exp2f(fmaf(st[qi][1], CUR.e4[1], -SHIFT2));        \
            p[2] = __builtin_amdgcn_exp2f(fmaf(st[qi][2], CUR.e4[2], -SHIFT2));        \
            p[3] = __builtin_amdgcn_exp2f(fmaf(st[qi][3], CUR.e4[3], -SHIFT2));        \
            pk[qi] = __builtin_bit_cast(short4v, __builtin_convertvector(p, bf16x4));  \
        }                                                                              \
        setprio1();                                                                    \
        _Pragma("unroll")                                                              \
        for (int qi = 0; qi < QI_; qi++) {                                             \
            o2[qi][0] = mfma16_bf16(CUR.va0, pk[qi], o2[qi][0]);                       \
            o2[qi][1] = mfma16_bf16(CUR.va1, pk[qi], o2[qi][1]);                       \
            o2[qi][2] = mfma16_bf16(CUR.va2, pk[qi], o2[qi][2]);                       \
            o2[qi][3] = mfma16_bf16(CUR.va3, pk[qi], o2[qi][3]);                       \
            lacc[qi]  = mfma16_bf16(ones,    pk[qi], lacc[qi]);                        \
        }                                                                              \
        setprio0();                                                                    \
    }

    for (int t = 0; t < NT_; t += 2) {
        ATTN_STEP(t,     fA, fB);
        ATTN_STEP(t + 1, fB, fA);
    }
#undef ATTN_STEP

    __syncthreads();   // all waves done with LDS K/V buffers before overlay

    // ---- epilogue: cross-wave reduction of O^T partials and denominators ----
    float* o_red0 = (float*)smem;            // [48 q][68 c]
    float* o_red1 = o_red0 + QT_*68;
    float* l_red  = o_red1 + QT_*68;         // [4][48]

    if (lane < 16) {
        #pragma unroll
        for (int qi = 0; qi < QI_; qi++) l_red[wave*QT_ + qi*16 + l16] = lacc[qi][0];
    }
    if (wave < 2) {
        float* od = (wave == 0) ? o_red0 : o_red1;
        #pragma unroll
        for (int qi = 0; qi < QI_; qi++)
            #pragma unroll
            for (int ct = 0; ct < 4; ct++)
                *(f32x4*)&od[(qi*16 + l16)*68 + ct*16 + quad*4] = o2[qi][ct];
    }
    __syncthreads();
    if (wave >= 2) {
        float* od = (wave == 2) ? o_red0 : o_red1;
        #pragma unroll
        for (int qi = 0; qi < QI_; qi++)
            #pragma unroll
            for (int ct = 0; ct < 4; ct++) {
                f32x4* p = (f32x4*)&od[(qi*16 + l16)*68 + ct*16 + quad*4];
                *p += o2[qi][ct];
            }
    }
    __syncthreads();
    if (tid < QT_) {
        float s = (l_red[tid] + l_red[QT_ + tid]) + (l_red[2*QT_ + tid] + l_red[3*QT_ + tid]);
        l_red[tid] = 1.f / s;
    }
    __syncthreads();

    float gmm = gamma_p[0];
    int c = tid >> 2, q4 = tid & 3;
    const float* xrow = x + ((size_t)b*C_ + c)*N_ + n_base;
    float* orow = out + ((size_t)b*C_ + c)*N_ + n_base;
    #pragma unroll
    for (int i = 0; i < QI_; i++) {
        int q0 = q4*4 + i*16;
        float4 xv = *(const float4*)(xrow + q0);
        float4 ov;
        float v0 = (o_red0[(q0+0)*68 + c] + o_red1[(q0+0)*68 + c]) * l_red[q0+0];
        float v1 = (o_red0[(q0+1)*68 + c] + o_red1[(q0+1)*68 + c]) * l_red[q0+1];
        float v2 = (o_red0[(q0+2)*68 + c] + o_red1[(q0+2)*68 + c]) * l_red[q0+2];
        float v3 = (o_red0[(q0+3)*68 + c] + o_red1[(q0+3)*68 + c]) * l_red[q0+3];
        ov.x = fmaf(gmm, v0, xv.x);
        ov.y = fmaf(gmm, v1, xv.y);
        ov.z = fmaf(gmm, v2, xv.z);
        ov.w = fmaf(gmm, v3, xv.w);
        *(float4*)(orow + q0) = ov;
    }
}

extern "C" void kernel_launch(void* const* d_in, const int* in_sizes, int n_in,
                              void* d_out, int out_size, void* d_ws, size_t ws_size,
                              hipStream_t stream) {
    const float* c2    = (const float*)d_in[0];
    const float* x     = (const float*)d_in[1];
    const float* w_ea1 = (const float*)d_in[2];
    const float* bn_w  = (const float*)d_in[3];
    const float* bn_b  = (const float*)d_in[4];
    const float* bn_m  = (const float*)d_in[5];
    const float* bn_v  = (const float*)d_in[6];
    const float* w_ea2 = (const float*)d_in[7];
    const float* b_ea2 = (const float*)d_in[8];
    const float* w_q   = (const float*)d_in[9];
    const float* b_q   = (const float*)d_in[10];
    const float* gamma = (const float*)d_in[11];
    float* out = (float*)d_out;

    char* ws = (char*)d_ws;
    float* ea            = (float*)(ws + 0);                // 36864 B
    unsigned short* kb   = (unsigned short*)(ws + 36864);   // 1179648 B
    unsigned short* vb   = (unsigned short*)(ws + 1216512); // 1179648 B

    prep_kernel<<<dim3((B_*M_)/32), dim3(256), 0, stream>>>(x, c2, w_q, b_q,
        w_ea1, bn_w, bn_b, bn_m, bn_v, w_ea2, b_ea2, kb, vb, ea);
    attn_kernel<<<dim3(B_*QB_), dim3(256), 0, stream>>>(w_q, b_q, kb, vb, ea, x, gamma, out);
}

// Round 10
// 148.036 us; speedup vs baseline: 1.0285x; 1.0285x over previous
//
#include <hip/hip_runtime.h>
#include <stdint.h>

#define B_ 4
#define C_ 64
#define H_ 96
#define W_ 96
#define HP_ 48
#define WP_ 48
#define N_ (H_*W_)      // 9216
#define M_ (HP_*WP_)    // 2304
#define KD_ 64
#define OD_ 64
#define BN_EPS 1e-5f
#define LOG2E 1.4426950408889634f
#define SHIFT2 28.853900817779268f   // 20 * LOG2E
#define QT_ 48                        // q-tile: 768 blocks = exactly 3/CU
#define QI_ (QT_/16)                  // 3 q-frags per block
#define QB_ (N_/QT_)                  // 192 q-tiles per batch
#define NT_ (M_/64)                   // 36 m-tiles (even — 2x unroll relies on it)

typedef __bf16 bf16_t;
typedef bf16_t bf16x8 __attribute__((ext_vector_type(8)));
typedef bf16_t bf16x4 __attribute__((ext_vector_type(4)));
typedef float f32x4 __attribute__((ext_vector_type(4)));
typedef short short4v __attribute__((ext_vector_type(4)));

static __device__ __forceinline__ unsigned short f2bf(float f) {
    unsigned int u = __builtin_bit_cast(unsigned int, f);
    u += 0x7fffu + ((u >> 16) & 1u);
    return (unsigned short)(u >> 16);
}

static __device__ __forceinline__ f32x4 mfma16_bf16(short4v a, short4v b, f32x4 c) {
#if __has_builtin(__builtin_amdgcn_mfma_f32_16x16x16bf16_1k)
    return __builtin_amdgcn_mfma_f32_16x16x16bf16_1k(a, b, c, 0, 0, 0);
#else
    return c;  // host pass only — never executed on device
#endif
}

// async global->LDS DMA, 16B per lane. LDS dest must be linear.
static __device__ __forceinline__ void gl_lds16(const unsigned short* g, unsigned short* l) {
#if __has_builtin(__builtin_amdgcn_global_load_lds)
    __builtin_amdgcn_global_load_lds(
        (const __attribute__((address_space(1))) unsigned int*)(const void*)g,
        (__attribute__((address_space(3))) unsigned int*)(void*)l, 16, 0, 0);
#endif
}

static __device__ __forceinline__ void setprio1() {
#if __has_builtin(__builtin_amdgcn_s_setprio)
    __builtin_amdgcn_s_setprio(1);
#endif
}
static __device__ __forceinline__ void setprio0() {
#if __has_builtin(__builtin_amdgcn_s_setprio)
    __builtin_amdgcn_s_setprio(0);
#endif
}
static __device__ __forceinline__ void schedbar0() {
#if __has_builtin(__builtin_amdgcn_sched_barrier)
    __builtin_amdgcn_sched_barrier(0);
#endif
}
static __device__ __forceinline__ void rawbar() {
#if __has_builtin(__builtin_amdgcn_s_barrier)
    __builtin_amdgcn_s_barrier();
#else
    __syncthreads();
#endif
}

// ---------------- Kernel 1: fused pool(x,c2) + key conv + edge attention ----------------
__global__ __launch_bounds__(256) void prep_kernel(
    const float* __restrict__ x, const float* __restrict__ c2,
    const float* __restrict__ wq, const float* __restrict__ bq,
    const float* __restrict__ w1, const float* __restrict__ bnw, const float* __restrict__ bnb,
    const float* __restrict__ bnm, const float* __restrict__ bnv,
    const float* __restrict__ w2, const float* __restrict__ b2,
    unsigned short* __restrict__ kb, unsigned short* __restrict__ vb, float* __restrict__ ea) {

    __shared__ float lw1[OD_*2*C_];
    __shared__ float lwq[KD_*C_];
    __shared__ float xs[C_*33];
    __shared__ float c2s[C_*33];
    __shared__ float red[8][32];

    int tid = threadIdx.x;
    int b = blockIdx.x / 72;
    int m0 = (blockIdx.x % 72) * 32;

    for (int i = tid; i < OD_*2*C_; i += 256) lw1[i] = w1[i];
    for (int i = tid; i < KD_*C_; i += 256) lwq[i] = wq[i];
    for (int j = tid; j < 2048; j += 256) {
        int c = j >> 5, p = j & 31;
        int m = m0 + p;
        int hp = m / WP_, wp = m % WP_;
        size_t base = ((size_t)(b*C_ + c)*H_ + 2*hp)*W_ + 2*wp;
        const float* px = x + base;
        float mx = fmaxf(fmaxf(px[0], px[1]), fmaxf(px[W_], px[W_+1]));
        xs[c*33 + p] = mx;
        vb[(size_t)(b*C_ + c)*M_ + m] = f2bf(mx);
        const float* pc = c2 + base;
        c2s[c*33 + p] = fmaxf(fmaxf(pc[0], pc[1]), fmaxf(pc[W_], pc[W_+1]));
    }
    __syncthreads();

    int ml = tid & 31, oz = tid >> 5;
    int m = m0 + ml;

    float h[8] = {0,0,0,0,0,0,0,0};
    for (int c = 0; c < C_; c += 4) {
        float x0 = xs[c*33+ml], x1 = xs[(c+1)*33+ml], x2 = xs[(c+2)*33+ml], x3 = xs[(c+3)*33+ml];
        #pragma unroll
        for (int oi = 0; oi < 8; oi++) {
            const float4 wv = *(const float4*)&lwq[(oz*8 + oi)*C_ + c];
            h[oi] = fmaf(wv.x, x0, fmaf(wv.y, x1, fmaf(wv.z, x2, fmaf(wv.w, x3, h[oi]))));
        }
    }
    unsigned short tmp[8];
    #pragma unroll
    for (int oi = 0; oi < 8; oi++) tmp[oi] = f2bf(h[oi] + bq[oz*8 + oi]);
    *(uint4*)&kb[((size_t)b*M_ + m)*KD_ + oz*8] = *(const uint4*)tmp;

    float g[8] = {0,0,0,0,0,0,0,0};
    for (int c = 0; c < 2*C_; c += 4) {
        const float* srcb = (c < C_) ? &c2s[c*33] : &xs[(c - C_)*33];
        float x0 = srcb[ml], x1 = srcb[33+ml], x2 = srcb[66+ml], x3 = srcb[99+ml];
        #pragma unroll
        for (int oi = 0; oi < 8; oi++) {
            const float4 wv = *(const float4*)&lw1[(oz*8 + oi)*(2*C_) + c];
            g[oi] = fmaf(wv.x, x0, fmaf(wv.y, x1, fmaf(wv.z, x2, fmaf(wv.w, x3, g[oi]))));
        }
    }
    float z = 0.f;
    #pragma unroll
    for (int oi = 0; oi < 8; oi++) {
        int o = oz*8 + oi;
        float sc = bnw[o] * rsqrtf(bnv[o] + BN_EPS);
        float t = (g[oi] - bnm[o]) * sc + bnb[o];
        z += w2[o] * fmaxf(t, 0.f);
    }
    red[oz][ml] = z;
    __syncthreads();
    if (oz == 0) {
        float s = b2[0];
        #pragma unroll
        for (int i = 0; i < 8; i++) s += red[i][ml];
        ea[(size_t)b*M_ + m] = LOG2E / (1.f + __builtin_amdgcn_exp2f(-s * LOG2E));
    }
}

// ---------------- Kernel 2: flash attention with MFMA q-conv prologue ----------------
// R10: q-conv moved to the matrix pipe. R8/R9 VALU conv = 768 FMA + 192
// ds_read_b128/thread (~6.3us, VALU+LDS-pipe bound). Now: compensated bf16
// MFMA (W=Wh+Wl, x=xh+xl bf16; q = Wh·xh + Wl·xh + Wh·xl, fp32 accum;
// dropped Wl·xl ~2^-18 rel -> q's bf16 rounding unchanged). 18 MFMA/wave,
// weights+x read from global (L2-hot, lane-coalesced), hi/lo split
// in-register, D written to qlds (swizzled, 1 ds_write_b64/n-tile).
// Also fixes the latent qlds/ea overwrite race with an explicit barrier
// between qf frag reads and the ea copy.
// Main loop unchanged (R6): reg-level 1-deep frag pipeline, counted vmcnt,
// one barrier/step, setprio, ones-MFMA denominator.
__global__ __launch_bounds__(256, 3) void attn_kernel(
    const float* __restrict__ wq, const float* __restrict__ bq,
    const unsigned short* __restrict__ kb, const unsigned short* __restrict__ vb,
    const float* __restrict__ ea, const float* __restrict__ x,
    const float* __restrict__ gamma_p, float* __restrict__ out) {

    // dbuf: [k 8192 | v 8192] x2 = 32768 B, ea 9216 B -> 41984 B
    // prologue overlay: qlds 6144 @32768 (ea region, consumed before ea copy)
    // epilogue overlay: o_red 2*48*68*4=26112 + l_red 768 = 26880 B (fits)
    __shared__ __align__(16) char smem[41984];

    int tid = threadIdx.x;
    int wave = tid >> 6, lane = tid & 63, quad = lane >> 4, l16 = lane & 15;
    int blk = blockIdx.x;
    int b = (blk & 7) >> 1;                       // batch pinned to XCD pair
    int n_base = ((blk & 1) * (QB_/2) + (blk >> 3)) * QT_;
    int xsw = l16 & 7;

    // ---- fused q-conv via compensated bf16 MFMA ----
    unsigned short* qlds = (unsigned short*)(smem + 32768); // [48 n][64 k] bf16 swz
    {
        const float* xb = x + (size_t)b*C_*N_ + n_base;
        // A-frags: W rows = this wave's 16 k-channels; A[row=l16][c=quad*8+j (+32h)]
        bf16x8 wh0, wh1, wl0, wl1;
        {
            float w8[8];
            unsigned short hs[8], ls[8];
            const float* wp0 = wq + (size_t)(wave*16 + l16)*C_ + quad*8;
            *(float4*)&w8[0] = *(const float4*)wp0;
            *(float4*)&w8[4] = *(const float4*)(wp0 + 4);
            #pragma unroll
            for (int j = 0; j < 8; j++) {
                hs[j] = f2bf(w8[j]);
                float hf = __builtin_bit_cast(float, (unsigned int)hs[j] << 16);
                ls[j] = f2bf(w8[j] - hf);
            }
            wh0 = __builtin_bit_cast(bf16x8, *(const uint4*)hs);
            wl0 = __builtin_bit_cast(bf16x8, *(const uint4*)ls);
            const float* wp1 = wp0 + 32;
            *(float4*)&w8[0] = *(const float4*)wp1;
            *(float4*)&w8[4] = *(const float4*)(wp1 + 4);
            #pragma unroll
            for (int j = 0; j < 8; j++) {
                hs[j] = f2bf(w8[j]);
                float hf = __builtin_bit_cast(float, (unsigned int)hs[j] << 16);
                ls[j] = f2bf(w8[j] - hf);
            }
            wh1 = __builtin_bit_cast(bf16x8, *(const uint4*)hs);
            wl1 = __builtin_bit_cast(bf16x8, *(const uint4*)ls);
        }
        float4 bq4 = *(const float4*)(bq + wave*16 + quad*4);

        f32x4 qacc[3];
        #pragma unroll
        for (int t = 0; t < 3; t++) qacc[t] = (f32x4){0.f,0.f,0.f,0.f};

        #pragma unroll
        for (int t = 0; t < 3; t++) {
            #pragma unroll
            for (int h = 0; h < 2; h++) {
                // B-frag: B[c = h*32 + quad*8 + j][n = t*16 + l16] from global x
                // (per instr: 16 consecutive n x 4 rows -> coalesced 64B segments)
                float v8[8];
                #pragma unroll
                for (int j = 0; j < 8; j++)
                    v8[j] = xb[(size_t)(h*32 + quad*8 + j)*N_ + t*16 + l16];
                unsigned short hs[8], ls[8];
                #pragma unroll
                for (int j = 0; j < 8; j++) {
                    hs[j] = f2bf(v8[j]);
                    float hf = __builtin_bit_cast(float, (unsigned int)hs[j] << 16);
                    ls[j] = f2bf(v8[j] - hf);
                }
                bf16x8 xh = __builtin_bit_cast(bf16x8, *(const uint4*)hs);
                bf16x8 xl = __builtin_bit_cast(bf16x8, *(const uint4*)ls);
                bf16x8 wh = h ? wh1 : wh0;   // h is unroll-constant
                bf16x8 wl = h ? wl1 : wl0;
#if __has_builtin(__builtin_amdgcn_mfma_f32_16x16x32_bf16)
                qacc[t] = __builtin_amdgcn_mfma_f32_16x16x32_bf16(wh, xh, qacc[t], 0, 0, 0);
                qacc[t] = __builtin_amdgcn_mfma_f32_16x16x32_bf16(wl, xh, qacc[t], 0, 0, 0);
                qacc[t] = __builtin_amdgcn_mfma_f32_16x16x32_bf16(wh, xl, qacc[t], 0, 0, 0);
#endif
            }
        }
        // D: col = n = l16 (+16t), row = k = wave*16 + quad*4 + r
        #pragma unroll
        for (int t = 0; t < 3; t++) {
            unsigned short q4[4];
            q4[0] = f2bf(qacc[t][0] + bq4.x);
            q4[1] = f2bf(qacc[t][1] + bq4.y);
            q4[2] = f2bf(qacc[t][2] + bq4.z);
            q4[3] = f2bf(qacc[t][3] + bq4.w);
            int n_abs = t*16 + l16;
            int kc = wave*2 + (quad >> 1);
            *(uint2*)&qlds[n_abs*64 + ((kc ^ (n_abs & 7)) << 3) + (quad & 1)*4] =
                *(const uint2*)q4;
        }
    }
    asm volatile("s_waitcnt lgkmcnt(0)" ::: "memory"); // qlds writes done (own wave)
    __syncthreads();                                   // all waves' q written

    // Q B-frags from the swizzled LDS scratch: B[col=q=qi*16+l16][k=quad*8+j]
    bf16x8 qf[QI_][2];
    #pragma unroll
    for (int qi = 0; qi < QI_; qi++) {
        const unsigned short* qp = qlds + (qi*16 + l16)*64;
        qf[qi][0] = __builtin_bit_cast(bf16x8, *(const uint4*)(qp + ((quad     ^ xsw) << 3)));
        qf[qi][1] = __builtin_bit_cast(bf16x8, *(const uint4*)(qp + (((quad+4) ^ xsw) << 3)));
    }
    asm volatile("s_waitcnt lgkmcnt(0)" ::: "memory"); // qf reads landed (own wave)
    __syncthreads();          // RACE FIX: all waves done reading qlds before ea copy

    f32x4 o2[QI_][4]; // O^T partial: [qi][ct]
    f32x4 lacc[QI_];  // denominator partials via ones-MFMA
    #pragma unroll
    for (int qi = 0; qi < QI_; qi++) {
        lacc[qi] = (f32x4){0.f,0.f,0.f,0.f};
        #pragma unroll
        for (int ct = 0; ct < 4; ct++) o2[qi][ct] = (f32x4){0.f,0.f,0.f,0.f};
    }
    const short one_bf = (short)0x3F80;  // bf16 1.0
    short4v ones = (short4v){one_bf, one_bf, one_bf, one_bf};

    const unsigned short* kbB = kb + (size_t)b*M_*KD_;
    const unsigned short* vbB = vb + (size_t)b*C_*M_;
    const float* eaB = ea + (size_t)b*M_;

    int srow = tid >> 3;                       // 0..31
    int ksw  = ((tid & 7) ^ (srow & 7)) << 3;  // swizzled src offset (shorts)

    auto STAGE = [&](int mb, char* kd, char* vd) {
        unsigned short* kds = (unsigned short*)kd;
        unsigned short* vds = (unsigned short*)vd;
        gl_lds16(kbB + (size_t)(mb + srow)*KD_      + ksw, kds + tid*8);
        gl_lds16(kbB + (size_t)(mb + srow + 32)*KD_ + ksw, kds + 2048 + tid*8);
        gl_lds16(vbB + (size_t)srow*M_      + mb + ksw, vds + tid*8);
        gl_lds16(vbB + (size_t)(srow+32)*M_ + mb + ksw, vds + 2048 + tid*8);
    };

    // ---- ea -> LDS; then stage tiles 0+1 ----
    {
        const f32x4* eaV = (const f32x4*)eaB;
        f32x4* eaL = (f32x4*)(smem + 32768);
        for (int i = tid; i < M_/4; i += 256) eaL[i] = eaV[i];
    }
    asm volatile("s_waitcnt lgkmcnt(0)" ::: "memory"); // ea ds_writes done (own wave)
    __syncthreads();                                   // all waves' ea visible
    STAGE(0,  smem,          smem + 8192);
    STAGE(64, smem + 16384,  smem + 16384 + 8192);
    asm volatile("s_waitcnt vmcnt(4)" ::: "memory");   // tile0 DMA done (own wave)
    rawbar();                                          // => all waves' tile0 done
    asm volatile("" ::: "memory");

    const float* lds_ea = (const float*)(smem + 32768);
    int krow = wave*16 + l16;

    // frag double-buffer: two NAMED sets (constant field access only)
    struct FragSet { bf16x8 kf0, kf1; short4v va0, va1, va2, va3; f32x4 e4; };
    FragSet fA, fB;

    // read frag set for tile 0 into fA (from buf0)
    {
        unsigned short* kc = (unsigned short*)smem;
        unsigned short* vc = (unsigned short*)(smem + 8192);
        fA.e4  = *(const f32x4*)&lds_ea[0*64 + wave*16 + quad*4];
        fA.kf0 = __builtin_bit_cast(bf16x8, *(const uint4*)(kc + krow*KD_ + (((quad  ) ^ xsw) << 3)));
        fA.kf1 = __builtin_bit_cast(bf16x8, *(const uint4*)(kc + krow*KD_ + (((quad+4) ^ xsw) << 3)));
        fA.va0 = *(const short4v*)(vc + (0*16 + l16)*64 + (((wave*2 + (quad>>1)) ^ xsw) << 3) + (quad&1)*4);
        fA.va1 = *(const short4v*)(vc + (1*16 + l16)*64 + (((wave*2 + (quad>>1)) ^ xsw) << 3) + (quad&1)*4);
        fA.va2 = *(const short4v*)(vc + (2*16 + l16)*64 + (((wave*2 + (quad>>1)) ^ xsw) << 3) + (quad&1)*4);
        fA.va3 = *(const short4v*)(vc + (3*16 + l16)*64 + (((wave*2 + (quad>>1)) ^ xsw) << 3) + (quad&1)*4);
    }

// one pipeline step: compute tile T_ from CUR; prefetch T_+1 frags into NXT
#define ATTN_STEP(T_, CUR, NXT)                                                        \
    {                                                                                  \
        const int t_ = (T_);                                                           \
        if (t_ < NT_ - 1) {                                                            \
            asm volatile("s_waitcnt vmcnt(0)" ::: "memory");  /* tile t_+1 DMA done */ \
            schedbar0();                                                               \
            rawbar();                               /* acquire buf[(t_+1)&1], release buf[t_&1] */ \
            asm volatile("" ::: "memory");                                             \
            schedbar0();                                                               \
            if (t_ + 2 < NT_) {                                                        \
                char* nb = smem + (t_ & 1) * 16384;                                    \
                STAGE((t_ + 2) * 64, nb, nb + 8192);                                   \
            }                                                                          \
            unsigned short* kc_ = (unsigned short*)(smem + ((t_ + 1) & 1) * 16384);    \
            unsigned short* vc_ = (unsigned short*)(smem + ((t_ + 1) & 1) * 16384 + 8192); \
            NXT.e4  = *(const f32x4*)&lds_ea[(t_ + 1)*64 + wave*16 + quad*4];          \
            NXT.kf0 = __builtin_bit_cast(bf16x8, *(const uint4*)(kc_ + krow*KD_ + (((quad  ) ^ xsw) << 3))); \
            NXT.kf1 = __builtin_bit_cast(bf16x8, *(const uint4*)(kc_ + krow*KD_ + (((quad+4) ^ xsw) << 3))); \
            NXT.va0 = *(const short4v*)(vc_ + (0*16 + l16)*64 + (((wave*2 + (quad>>1)) ^ xsw) << 3) + (quad&1)*4); \
            NXT.va1 = *(const short4v*)(vc_ + (1*16 + l16)*64 + (((wave*2 + (quad>>1)) ^ xsw) << 3) + (quad&1)*4); \
            NXT.va2 = *(const short4v*)(vc_ + (2*16 + l16)*64 + (((wave*2 + (quad>>1)) ^ xsw) << 3) + (quad&1)*4); \
            NXT.va3 = *(const short4v*)(vc_ + (3*16 + l16)*64 + (((wave*2 + (quad>>1)) ^ xsw) << 3) + (quad&1)*4); \
            schedbar0();                                                               \
            asm volatile("s_waitcnt lgkmcnt(7)" ::: "memory"); /* CUR reads landed */  \
            schedbar0();                                                               \
        } else {                                                                       \
            schedbar0();                                                               \
            asm volatile("s_waitcnt lgkmcnt(0)" ::: "memory"); /* last frag set */     \
            schedbar0();                                                               \
        }                                                                              \
        /* ---- compute tile t_ from CUR (register-only) ---- */                       \
        f32x4 st[QI_];                                                                 \
        setprio1();                                                                    \
        _Pragma("unroll")                                                              \
        for (int qi = 0; qi < QI_; qi++) {                                             \
            f32x4 z = (f32x4){0.f,0.f,0.f,0.f};                                        \
            z = __builtin_amdgcn_mfma_f32_16x16x32_bf16(CUR.kf0, qf[qi][0], z, 0, 0, 0); \
            z = __builtin_amdgcn_mfma_f32_16x16x32_bf16(CUR.kf1, qf[qi][1], z, 0, 0, 0); \
            st[qi] = z;                                                                \
        }                                                                              \
        setprio0();                                                                    \
        short4v pk[QI_];                                                               \
        _Pragma("unroll")                                                              \
        for (int qi = 0; qi < QI_; qi++) {                                             \
            f32x4 p;                                                                   \
            p[0] = __builtin_amdgcn_exp2f(fmaf(st[qi][0], CUR.e4[0], -SHIFT2));        \
            p[1] = __builtin_amdgcn_exp2f(fmaf(st[qi][1], CUR.e4[1], -SHIFT2));        \
            p[2] = __builtin_amdgcn_exp2f(fmaf(st[qi][2], CUR.e4[2], -SHIFT2));        \
            p[3] = __builtin_amdgcn_exp2f(fmaf(st[qi][3], CUR.e4[3], -SHIFT2));        \
            pk[qi] = __builtin_bit_cast(short4v, __builtin_convertvector(p, bf16x4));  \
        }                                                                              \
        setprio1();                                                                    \
        _Pragma("unroll")                                                              \
        for (int qi = 0; qi < QI_; qi++) {                                             \
            o2[qi][0] = mfma16_bf16(CUR.va0, pk[qi], o2[qi][0]);                       \
            o2[qi][1] = mfma16_bf16(CUR.va1, pk[qi], o2[qi][1]);                       \
            o2[qi][2] = mfma16_bf16(CUR.va2, pk[qi], o2[qi][2]);                       \
            o2[qi][3] = mfma16_bf16(CUR.va3, pk[qi], o2[qi][3]);                       \
            lacc[qi]  = mfma16_bf16(ones,    pk[qi], lacc[qi]);                        \
        }                                                                              \
        setprio0();                                                                    \
    }

    for (int t = 0; t < NT_; t += 2) {
        ATTN_STEP(t,     fA, fB);
        ATTN_STEP(t + 1, fB, fA);
    }
#undef ATTN_STEP

    __syncthreads();   // all waves done with LDS K/V buffers before overlay

    // ---- epilogue: cross-wave reduction of O^T partials and denominators ----
    float* o_red0 = (float*)smem;            // [48 q][68 c]
    float* o_red1 = o_red0 + QT_*68;
    float* l_red  = o_red1 + QT_*68;         // [4][48]

    if (lane < 16) {
        #pragma unroll
        for (int qi = 0; qi < QI_; qi++) l_red[wave*QT_ + qi*16 + l16] = lacc[qi][0];
    }
    if (wave < 2) {
        float* od = (wave == 0) ? o_red0 : o_red1;
        #pragma unroll
        for (int qi = 0; qi < QI_; qi++)
            #pragma unroll
            for (int ct = 0; ct < 4; ct++)
                *(f32x4*)&od[(qi*16 + l16)*68 + ct*16 + quad*4] = o2[qi][ct];
    }
    __syncthreads();
    if (wave >= 2) {
        float* od = (wave == 2) ? o_red0 : o_red1;
        #pragma unroll
        for (int qi = 0; qi < QI_; qi++)
            #pragma unroll
            for (int ct = 0; ct < 4; ct++) {
                f32x4* p = (f32x4*)&od[(qi*16 + l16)*68 + ct*16 + quad*4];
                *p += o2[qi][ct];
            }
    }
    __syncthreads();
    if (tid < QT_) {
        float s = (l_red[tid] + l_red[QT_ + tid]) + (l_red[2*QT_ + tid] + l_red[3*QT_ + tid]);
        l_red[tid] = 1.f / s;
    }
    __syncthreads();

    float gmm = gamma_p[0];
    int c = tid >> 2, q4 = tid & 3;
    const float* xrow = x + ((size_t)b*C_ + c)*N_ + n_base;
    float* orow = out + ((size_t)b*C_ + c)*N_ + n_base;
    #pragma unroll
    for (int i = 0; i < QI_; i++) {
        int q0 = q4*4 + i*16;
        float4 xv = *(const float4*)(xrow + q0);
        float4 ov;
        float v0 = (o_red0[(q0+0)*68 + c] + o_red1[(q0+0)*68 + c]) * l_red[q0+0];
        float v1 = (o_red0[(q0+1)*68 + c] + o_red1[(q0+1)*68 + c]) * l_red[q0+1];
        float v2 = (o_red0[(q0+2)*68 + c] + o_red1[(q0+2)*68 + c]) * l_red[q0+2];
        float v3 = (o_red0[(q0+3)*68 + c] + o_red1[(q0+3)*68 + c]) * l_red[q0+3];
        ov.x = fmaf(gmm, v0, xv.x);
        ov.y = fmaf(gmm, v1, xv.y);
        ov.z = fmaf(gmm, v2, xv.z);
        ov.w = fmaf(gmm, v3, xv.w);
        *(float4*)(orow + q0) = ov;
    }
}

extern "C" void kernel_launch(void* const* d_in, const int* in_sizes, int n_in,
                              void* d_out, int out_size, void* d_ws, size_t ws_size,
                              hipStream_t stream) {
    const float* c2    = (const float*)d_in[0];
    const float* x     = (const float*)d_in[1];
    const float* w_ea1 = (const float*)d_in[2];
    const float* bn_w  = (const float*)d_in[3];
    const float* bn_b  = (const float*)d_in[4];
    const float* bn_m  = (const float*)d_in[5];
    const float* bn_v  = (const float*)d_in[6];
    const float* w_ea2 = (const float*)d_in[7];
    const float* b_ea2 = (const float*)d_in[8];
    const float* w_q   = (const float*)d_in[9];
    const float* b_q   = (const float*)d_in[10];
    const float* gamma = (const float*)d_in[11];
    float* out = (float*)d_out;

    char* ws = (char*)d_ws;
    float* ea            = (float*)(ws + 0);                // 36864 B
    unsigned short* kb   = (unsigned short*)(ws + 36864);   // 1179648 B
    unsigned short* vb   = (unsigned short*)(ws + 1216512); // 1179648 B

    prep_kernel<<<dim3((B_*M_)/32), dim3(256), 0, stream>>>(x, c2, w_q, b_q,
        w_ea1, bn_w, bn_b, bn_m, bn_v, w_ea2, b_ea2, kb, vb, ea);
    attn_kernel<<<dim3(B_*QB_), dim3(256), 0, stream>>>(w_q, b_q, kb, vb, ea, x, gamma, out);
}

// Round 11
// 147.998 us; speedup vs baseline: 1.0288x; 1.0003x over previous
//
#include <hip/hip_runtime.h>
#include <stdint.h>

#define B_ 4
#define C_ 64
#define H_ 96
#define W_ 96
#define HP_ 48
#define WP_ 48
#define N_ (H_*W_)      // 9216
#define M_ (HP_*WP_)    // 2304
#define KD_ 64
#define OD_ 64
#define BN_EPS 1e-5f
#define LOG2E 1.4426950408889634f
#define SHIFT2 28.853900817779268f   // 20 * LOG2E
#define QT_ 48                        // q-tile: 768 blocks
#define QI_ (QT_/16)                  // 3 q-frags per block
#define QB_ (N_/QT_)                  // 192 q-tiles per batch
#define KVB_ 128                      // R11: m-tile 64 -> 128 (half the sync steps)
#define NT2_ (M_/KVB_)                // 18 m-tiles (even — 2x unroll relies on it)
#define KBUF_ 16384                   // K tile bytes: 128 rows x 64 k x 2
#define BUF_ 32768                    // K + V per buffer
#define EAOFF_ 65536                  // ea after 2 buffers
// total smem = 65536 + 9216 = 74752 -> 2 blocks/CU

typedef __bf16 bf16_t;
typedef bf16_t bf16x8 __attribute__((ext_vector_type(8)));
typedef bf16_t bf16x4 __attribute__((ext_vector_type(4)));
typedef float f32x4 __attribute__((ext_vector_type(4)));
typedef short short4v __attribute__((ext_vector_type(4)));
typedef short short8v __attribute__((ext_vector_type(8)));

static __device__ __forceinline__ unsigned short f2bf(float f) {
    unsigned int u = __builtin_bit_cast(unsigned int, f);
    u += 0x7fffu + ((u >> 16) & 1u);
    return (unsigned short)(u >> 16);
}

// async global->LDS DMA, 16B per lane. LDS dest must be linear per wave;
// the GLOBAL source is per-lane (this is what makes the staged row
// permutation and chunk swizzle free).
static __device__ __forceinline__ void gl_lds16(const unsigned short* g, unsigned short* l) {
#if __has_builtin(__builtin_amdgcn_global_load_lds)
    __builtin_amdgcn_global_load_lds(
        (const __attribute__((address_space(1))) unsigned int*)(const void*)g,
        (__attribute__((address_space(3))) unsigned int*)(void*)l, 16, 0, 0);
#endif
}

static __device__ __forceinline__ void setprio1() {
#if __has_builtin(__builtin_amdgcn_s_setprio)
    __builtin_amdgcn_s_setprio(1);
#endif
}
static __device__ __forceinline__ void setprio0() {
#if __has_builtin(__builtin_amdgcn_s_setprio)
    __builtin_amdgcn_s_setprio(0);
#endif
}
static __device__ __forceinline__ void schedbar0() {
#if __has_builtin(__builtin_amdgcn_sched_barrier)
    __builtin_amdgcn_sched_barrier(0);
#endif
}
static __device__ __forceinline__ void rawbar() {
#if __has_builtin(__builtin_amdgcn_s_barrier)
    __builtin_amdgcn_s_barrier();
#else
    __syncthreads();
#endif
}

// ---------------- Kernel 1: fused pool(x,c2) + key conv + edge attention ----------------
__global__ __launch_bounds__(256) void prep_kernel(
    const float* __restrict__ x, const float* __restrict__ c2,
    const float* __restrict__ wq, const float* __restrict__ bq,
    const float* __restrict__ w1, const float* __restrict__ bnw, const float* __restrict__ bnb,
    const float* __restrict__ bnm, const float* __restrict__ bnv,
    const float* __restrict__ w2, const float* __restrict__ b2,
    unsigned short* __restrict__ kb, unsigned short* __restrict__ vb, float* __restrict__ ea) {

    __shared__ float lw1[OD_*2*C_];
    __shared__ float lwq[KD_*C_];
    __shared__ float xs[C_*33];
    __shared__ float c2s[C_*33];
    __shared__ float red[8][32];

    int tid = threadIdx.x;
    int b = blockIdx.x / 72;
    int m0 = (blockIdx.x % 72) * 32;

    for (int i = tid; i < OD_*2*C_; i += 256) lw1[i] = w1[i];
    for (int i = tid; i < KD_*C_; i += 256) lwq[i] = wq[i];
    for (int j = tid; j < 2048; j += 256) {
        int c = j >> 5, p = j & 31;
        int m = m0 + p;
        int hp = m / WP_, wp = m % WP_;
        size_t base = ((size_t)(b*C_ + c)*H_ + 2*hp)*W_ + 2*wp;
        const float* px = x + base;
        float mx = fmaxf(fmaxf(px[0], px[1]), fmaxf(px[W_], px[W_+1]));
        xs[c*33 + p] = mx;
        vb[(size_t)(b*C_ + c)*M_ + m] = f2bf(mx);
        const float* pc = c2 + base;
        c2s[c*33 + p] = fmaxf(fmaxf(pc[0], pc[1]), fmaxf(pc[W_], pc[W_+1]));
    }
    __syncthreads();

    int ml = tid & 31, oz = tid >> 5;
    int m = m0 + ml;

    float h[8] = {0,0,0,0,0,0,0,0};
    for (int c = 0; c < C_; c += 4) {
        float x0 = xs[c*33+ml], x1 = xs[(c+1)*33+ml], x2 = xs[(c+2)*33+ml], x3 = xs[(c+3)*33+ml];
        #pragma unroll
        for (int oi = 0; oi < 8; oi++) {
            const float4 wv = *(const float4*)&lwq[(oz*8 + oi)*C_ + c];
            h[oi] = fmaf(wv.x, x0, fmaf(wv.y, x1, fmaf(wv.z, x2, fmaf(wv.w, x3, h[oi]))));
        }
    }
    unsigned short tmp[8];
    #pragma unroll
    for (int oi = 0; oi < 8; oi++) tmp[oi] = f2bf(h[oi] + bq[oz*8 + oi]);
    *(uint4*)&kb[((size_t)b*M_ + m)*KD_ + oz*8] = *(const uint4*)tmp;

    float g[8] = {0,0,0,0,0,0,0,0};
    for (int c = 0; c < 2*C_; c += 4) {
        const float* srcb = (c < C_) ? &c2s[c*33] : &xs[(c - C_)*33];
        float x0 = srcb[ml], x1 = srcb[33+ml], x2 = srcb[66+ml], x3 = srcb[99+ml];
        #pragma unroll
        for (int oi = 0; oi < 8; oi++) {
            const float4 wv = *(const float4*)&lw1[(oz*8 + oi)*(2*C_) + c];
            g[oi] = fmaf(wv.x, x0, fmaf(wv.y, x1, fmaf(wv.z, x2, fmaf(wv.w, x3, g[oi]))));
        }
    }
    float z = 0.f;
    #pragma unroll
    for (int oi = 0; oi < 8; oi++) {
        int o = oz*8 + oi;
        float sc = bnw[o] * rsqrtf(bnv[o] + BN_EPS);
        float t = (g[oi] - bnm[o]) * sc + bnb[o];
        z += w2[o] * fmaxf(t, 0.f);
    }
    red[oz][ml] = z;
    __syncthreads();
    if (oz == 0) {
        float s = b2[0];
        #pragma unroll
        for (int i = 0; i < 8; i++) s += red[i][ml];
        ea[(size_t)b*M_ + m] = LOG2E / (1.f + __builtin_amdgcn_exp2f(-s * LOG2E));
    }
}

// ---------------- Kernel 2: flash attention, 128-m tiles, K=32 PV ----------------
// R11: KVBLK 64->128. Per 128 m: 27 MFMA issues (vs 42), 10 ds_reads (vs 14,
// all b128), 1 barrier (vs 2), half the counted waits. Each wave owns 32 m.
// The K=32 PV B-frag (P[k=quad*8+j][q]) falls out with ZERO cross-lane ops:
// K staging places global row m = (i>>2)*8 + half*4 + (i&3) at LDS strip row
// i (per-lane gl_lds source), so the two QK strips' D-rows are exactly
// m = quad*8+{0..3} and quad*8+{4..7}; pk8 = [cvt(stA),cvt(stB)].
// V keeps natural m-order; va reads become contiguous ds_read_b128.
// LDS 74752 -> 2 blocks/CU, launch_bounds(256,2) (VGPR budget 256).
// Prologue (R10 MFMA q-conv) and epilogue unchanged.
__global__ __launch_bounds__(256, 2) void attn_kernel(
    const float* __restrict__ wq, const float* __restrict__ bq,
    const unsigned short* __restrict__ kb, const unsigned short* __restrict__ vb,
    const float* __restrict__ ea, const float* __restrict__ x,
    const float* __restrict__ gamma_p, float* __restrict__ out) {

    // [K 16384 | V 16384] x2 = 65536, ea 9216 -> 74752 B
    // prologue overlay: qlds 6144 @EAOFF_ (consumed before ea copy)
    // epilogue overlay: o_red 26112 + l_red 768 = 26880 B @0 (fits)
    __shared__ __align__(16) char smem[74752];

    int tid = threadIdx.x;
    int wave = tid >> 6, lane = tid & 63, quad = lane >> 4, l16 = lane & 15;
    int blk = blockIdx.x;
    int b = (blk & 7) >> 1;                       // batch pinned to XCD pair
    int n_base = ((blk & 1) * (QB_/2) + (blk >> 3)) * QT_;
    int xsw = l16 & 7;

    // ---- fused q-conv via compensated bf16 MFMA (R10, unchanged) ----
    unsigned short* qlds = (unsigned short*)(smem + EAOFF_); // [48 n][64 k] bf16 swz
    {
        const float* xb = x + (size_t)b*C_*N_ + n_base;
        bf16x8 wh0, wh1, wl0, wl1;
        {
            float w8[8];
            unsigned short hs[8], ls[8];
            const float* wp0 = wq + (size_t)(wave*16 + l16)*C_ + quad*8;
            *(float4*)&w8[0] = *(const float4*)wp0;
            *(float4*)&w8[4] = *(const float4*)(wp0 + 4);
            #pragma unroll
            for (int j = 0; j < 8; j++) {
                hs[j] = f2bf(w8[j]);
                float hf = __builtin_bit_cast(float, (unsigned int)hs[j] << 16);
                ls[j] = f2bf(w8[j] - hf);
            }
            wh0 = __builtin_bit_cast(bf16x8, *(const uint4*)hs);
            wl0 = __builtin_bit_cast(bf16x8, *(const uint4*)ls);
            const float* wp1 = wp0 + 32;
            *(float4*)&w8[0] = *(const float4*)wp1;
            *(float4*)&w8[4] = *(const float4*)(wp1 + 4);
            #pragma unroll
            for (int j = 0; j < 8; j++) {
                hs[j] = f2bf(w8[j]);
                float hf = __builtin_bit_cast(float, (unsigned int)hs[j] << 16);
                ls[j] = f2bf(w8[j] - hf);
            }
            wh1 = __builtin_bit_cast(bf16x8, *(const uint4*)hs);
            wl1 = __builtin_bit_cast(bf16x8, *(const uint4*)ls);
        }
        float4 bq4 = *(const float4*)(bq + wave*16 + quad*4);

        f32x4 qacc[3];
        #pragma unroll
        for (int t = 0; t < 3; t++) qacc[t] = (f32x4){0.f,0.f,0.f,0.f};

        #pragma unroll
        for (int t = 0; t < 3; t++) {
            #pragma unroll
            for (int h = 0; h < 2; h++) {
                float v8[8];
                #pragma unroll
                for (int j = 0; j < 8; j++)
                    v8[j] = xb[(size_t)(h*32 + quad*8 + j)*N_ + t*16 + l16];
                unsigned short hs[8], ls[8];
                #pragma unroll
                for (int j = 0; j < 8; j++) {
                    hs[j] = f2bf(v8[j]);
                    float hf = __builtin_bit_cast(float, (unsigned int)hs[j] << 16);
                    ls[j] = f2bf(v8[j] - hf);
                }
                bf16x8 xh = __builtin_bit_cast(bf16x8, *(const uint4*)hs);
                bf16x8 xl = __builtin_bit_cast(bf16x8, *(const uint4*)ls);
                bf16x8 wh = h ? wh1 : wh0;
                bf16x8 wl = h ? wl1 : wl0;
#if __has_builtin(__builtin_amdgcn_mfma_f32_16x16x32_bf16)
                qacc[t] = __builtin_amdgcn_mfma_f32_16x16x32_bf16(wh, xh, qacc[t], 0, 0, 0);
                qacc[t] = __builtin_amdgcn_mfma_f32_16x16x32_bf16(wl, xh, qacc[t], 0, 0, 0);
                qacc[t] = __builtin_amdgcn_mfma_f32_16x16x32_bf16(wh, xl, qacc[t], 0, 0, 0);
#endif
            }
        }
        #pragma unroll
        for (int t = 0; t < 3; t++) {
            unsigned short q4[4];
            q4[0] = f2bf(qacc[t][0] + bq4.x);
            q4[1] = f2bf(qacc[t][1] + bq4.y);
            q4[2] = f2bf(qacc[t][2] + bq4.z);
            q4[3] = f2bf(qacc[t][3] + bq4.w);
            int n_abs = t*16 + l16;
            int kc = wave*2 + (quad >> 1);
            *(uint2*)&qlds[n_abs*64 + ((kc ^ (n_abs & 7)) << 3) + (quad & 1)*4] =
                *(const uint2*)q4;
        }
    }
    asm volatile("s_waitcnt lgkmcnt(0)" ::: "memory"); // qlds writes done (own wave)
    __syncthreads();                                   // all waves' q written

    // Q B-frags: B[col=q=qi*16+l16][k=quad*8+j]
    bf16x8 qf[QI_][2];
    #pragma unroll
    for (int qi = 0; qi < QI_; qi++) {
        const unsigned short* qp = qlds + (qi*16 + l16)*64;
        qf[qi][0] = __builtin_bit_cast(bf16x8, *(const uint4*)(qp + ((quad     ^ xsw) << 3)));
        qf[qi][1] = __builtin_bit_cast(bf16x8, *(const uint4*)(qp + (((quad+4) ^ xsw) << 3)));
    }
    asm volatile("s_waitcnt lgkmcnt(0)" ::: "memory"); // qf reads landed (own wave)
    __syncthreads();          // all waves done reading qlds before ea copy

    f32x4 o2[QI_][4]; // O^T partial: [qi][ct]
    f32x4 lacc[QI_];  // denominator partials via ones-MFMA
    #pragma unroll
    for (int qi = 0; qi < QI_; qi++) {
        lacc[qi] = (f32x4){0.f,0.f,0.f,0.f};
        #pragma unroll
        for (int ct = 0; ct < 4; ct++) o2[qi][ct] = (f32x4){0.f,0.f,0.f,0.f};
    }
    const unsigned short ones_u[8] = {0x3F80,0x3F80,0x3F80,0x3F80,0x3F80,0x3F80,0x3F80,0x3F80};
    bf16x8 ones8 = __builtin_bit_cast(bf16x8, *(const uint4*)ones_u);

    const unsigned short* kbB = kb + (size_t)b*M_*KD_;
    const unsigned short* vbB = vb + (size_t)b*C_*M_;
    const float* eaB = ea + (size_t)b*M_;

    // ---- staging invariants ----
    // K: LDS row R = p*32 + r8 holds global m = mb + p*32 + mloc(r8);
    //    mloc = (ii>>2)*8 + half*4 + (ii&3) — the P-repack-free permutation.
    int r8  = tid >> 3;                       // 0..31
    int mloc = (((r8 & 15) >> 2) << 3) + ((r8 >> 4) << 2) + (r8 & 3);
    int kcs = ((tid & 7) ^ (r8 & 7)) << 3;    // K chunk swizzle (shorts)
    int c16 = tid >> 4;                       // 0..15 (V c-row within pass)
    int vcs = ((tid & 15) ^ (c16 & 7)) << 3;  // V chunk swizzle (shorts)

    auto STAGE = [&](int mb, char* buf) {
        unsigned short* kd = (unsigned short*)buf;
        unsigned short* vd = (unsigned short*)(buf + KBUF_);
        gl_lds16(kbB + (size_t)(mb +  0 + mloc)*KD_ + kcs, kd + 0*2048 + tid*8);
        gl_lds16(kbB + (size_t)(mb + 32 + mloc)*KD_ + kcs, kd + 1*2048 + tid*8);
        gl_lds16(kbB + (size_t)(mb + 64 + mloc)*KD_ + kcs, kd + 2*2048 + tid*8);
        gl_lds16(kbB + (size_t)(mb + 96 + mloc)*KD_ + kcs, kd + 3*2048 + tid*8);
        gl_lds16(vbB + (size_t)( 0 + c16)*M_ + mb + vcs, vd + 0*2048 + tid*8);
        gl_lds16(vbB + (size_t)(16 + c16)*M_ + mb + vcs, vd + 1*2048 + tid*8);
        gl_lds16(vbB + (size_t)(32 + c16)*M_ + mb + vcs, vd + 2*2048 + tid*8);
        gl_lds16(vbB + (size_t)(48 + c16)*M_ + mb + vcs, vd + 3*2048 + tid*8);
    };

    // ---- ea -> LDS; then stage tiles 0+1 ----
    {
        const f32x4* eaV = (const f32x4*)eaB;
        f32x4* eaL = (f32x4*)(smem + EAOFF_);
        for (int i = tid; i < M_/4; i += 256) eaL[i] = eaV[i];
    }
    asm volatile("s_waitcnt lgkmcnt(0)" ::: "memory"); // ea ds_writes done (own wave)
    __syncthreads();                                   // all waves' ea visible
    STAGE(0,    smem);
    STAGE(128,  smem + BUF_);
    asm volatile("s_waitcnt vmcnt(8)" ::: "memory");   // tile0's 8 DMA done (own wave)
    rawbar();                                          // => all waves' tile0 done
    asm volatile("" ::: "memory");

    const float* lds_ea = (const float*)(smem + EAOFF_);

    // read offsets (shorts)
    int kOffA0 = (wave*32 + l16)*64 + ((quad       ^ xsw) << 3);
    int kOffA1 = (wave*32 + l16)*64 + (((quad + 4) ^ xsw) << 3);
    int kOffB0 = kOffA0 + 16*64;
    int kOffB1 = kOffA1 + 16*64;
    int vch    = ((wave*4 + quad) ^ xsw) << 3;
    int eaIdx  = wave*32 + quad*8;

    // frag double-buffer: two NAMED sets (constant field access only)
    struct FragSet {
        bf16x8 kfA0, kfA1, kfB0, kfB1;
        bf16x8 va0, va1, va2, va3;
        f32x4 eA, eB;
    };
    FragSet fA, fB;

    // read frag set for tile 0 into fA (from buf0)
    {
        unsigned short* kc = (unsigned short*)smem;
        unsigned short* vc = (unsigned short*)(smem + KBUF_);
        fA.eA  = *(const f32x4*)&lds_ea[0*KVB_ + eaIdx];
        fA.eB  = *(const f32x4*)&lds_ea[0*KVB_ + eaIdx + 4];
        fA.kfA0 = __builtin_bit_cast(bf16x8, *(const uint4*)(kc + kOffA0));
        fA.kfA1 = __builtin_bit_cast(bf16x8, *(const uint4*)(kc + kOffA1));
        fA.kfB0 = __builtin_bit_cast(bf16x8, *(const uint4*)(kc + kOffB0));
        fA.kfB1 = __builtin_bit_cast(bf16x8, *(const uint4*)(kc + kOffB1));
        fA.va0 = __builtin_bit_cast(bf16x8, *(const uint4*)(vc + (0*16 + l16)*KVB_ + vch));
        fA.va1 = __builtin_bit_cast(bf16x8, *(const uint4*)(vc + (1*16 + l16)*KVB_ + vch));
        fA.va2 = __builtin_bit_cast(bf16x8, *(const uint4*)(vc + (2*16 + l16)*KVB_ + vch));
        fA.va3 = __builtin_bit_cast(bf16x8, *(const uint4*)(vc + (3*16 + l16)*KVB_ + vch));
    }

// one pipeline step: compute tile T_ from CUR; prefetch T_+1 frags into NXT
#define ATTN_STEP(T_, CUR, NXT)                                                        \
    {                                                                                  \
        const int t_ = (T_);                                                           \
        if (t_ < NT2_ - 1) {                                                           \
            asm volatile("s_waitcnt vmcnt(0)" ::: "memory");  /* tile t_+1 DMA done */ \
            schedbar0();                                                               \
            rawbar();                   /* acquire buf[(t_+1)&1], release buf[t_&1] */ \
            asm volatile("" ::: "memory");                                             \
            schedbar0();                                                               \
            if (t_ + 2 < NT2_) { STAGE((t_ + 2)*KVB_, smem + (t_ & 1)*BUF_); }         \
            unsigned short* kc_ = (unsigned short*)(smem + ((t_ + 1) & 1)*BUF_);       \
            unsigned short* vc_ = (unsigned short*)(smem + ((t_ + 1) & 1)*BUF_ + KBUF_); \
            NXT.eA  = *(const f32x4*)&lds_ea[(t_ + 1)*KVB_ + eaIdx];                   \
            NXT.eB  = *(const f32x4*)&lds_ea[(t_ + 1)*KVB_ + eaIdx + 4];               \
            NXT.kfA0 = __builtin_bit_cast(bf16x8, *(const uint4*)(kc_ + kOffA0));      \
            NXT.kfA1 = __builtin_bit_cast(bf16x8, *(const uint4*)(kc_ + kOffA1));      \
            NXT.kfB0 = __builtin_bit_cast(bf16x8, *(const uint4*)(kc_ + kOffB0));      \
            NXT.kfB1 = __builtin_bit_cast(bf16x8, *(const uint4*)(kc_ + kOffB1));      \
            NXT.va0 = __builtin_bit_cast(bf16x8, *(const uint4*)(vc_ + (0*16 + l16)*KVB_ + vch)); \
            NXT.va1 = __builtin_bit_cast(bf16x8, *(const uint4*)(vc_ + (1*16 + l16)*KVB_ + vch)); \
            NXT.va2 = __builtin_bit_cast(bf16x8, *(const uint4*)(vc_ + (2*16 + l16)*KVB_ + vch)); \
            NXT.va3 = __builtin_bit_cast(bf16x8, *(const uint4*)(vc_ + (3*16 + l16)*KVB_ + vch)); \
            schedbar0();                                                               \
            asm volatile("s_waitcnt lgkmcnt(10)" ::: "memory"); /* CUR reads landed */ \
            schedbar0();                                                               \
        } else {                                                                       \
            schedbar0();                                                               \
            asm volatile("s_waitcnt lgkmcnt(0)" ::: "memory");  /* last frag set */    \
            schedbar0();                                                               \
        }                                                                              \
        /* ---- compute tile t_ from CUR (register-only) ---- */                       \
        f32x4 stA[QI_], stB[QI_];                                                      \
        setprio1();                                                                    \
        _Pragma("unroll")                                                              \
        for (int qi = 0; qi < QI_; qi++) {                                             \
            f32x4 zA = (f32x4){0.f,0.f,0.f,0.f};                                       \
            zA = __builtin_amdgcn_mfma_f32_16x16x32_bf16(CUR.kfA0, qf[qi][0], zA, 0, 0, 0); \
            zA = __builtin_amdgcn_mfma_f32_16x16x32_bf16(CUR.kfA1, qf[qi][1], zA, 0, 0, 0); \
            stA[qi] = zA;                                                              \
            f32x4 zB = (f32x4){0.f,0.f,0.f,0.f};                                       \
            zB = __builtin_amdgcn_mfma_f32_16x16x32_bf16(CUR.kfB0, qf[qi][0], zB, 0, 0, 0); \
            zB = __builtin_amdgcn_mfma_f32_16x16x32_bf16(CUR.kfB1, qf[qi][1], zB, 0, 0, 0); \
            stB[qi] = zB;                                                              \
        }                                                                              \
        setprio0();                                                                    \
        bf16x8 pk[QI_];                                                                \
        _Pragma("unroll")                                                              \
        for (int qi = 0; qi < QI_; qi++) {                                             \
            f32x4 pA, pB;                                                              \
            pA[0] = __builtin_amdgcn_exp2f(fmaf(stA[qi][0], CUR.eA[0], -SHIFT2));      \
            pA[1] = __builtin_amdgcn_exp2f(fmaf(stA[qi][1], CUR.eA[1], -SHIFT2));      \
            pA[2] = __builtin_amdgcn_exp2f(fmaf(stA[qi][2], CUR.eA[2], -SHIFT2));      \
            pA[3] = __builtin_amdgcn_exp2f(fmaf(stA[qi][3], CUR.eA[3], -SHIFT2));      \
            pB[0] = __builtin_amdgcn_exp2f(fmaf(stB[qi][0], CUR.eB[0], -SHIFT2));      \
            pB[1] = __builtin_amdgcn_exp2f(fmaf(stB[qi][1], CUR.eB[1], -SHIFT2));      \
            pB[2] = __builtin_amdgcn_exp2f(fmaf(stB[qi][2], CUR.eB[2], -SHIFT2));      \
            pB[3] = __builtin_amdgcn_exp2f(fmaf(stB[qi][3], CUR.eB[3], -SHIFT2));      \
            short4v pa = __builtin_bit_cast(short4v, __builtin_convertvector(pA, bf16x4)); \
            short4v pb = __builtin_bit_cast(short4v, __builtin_convertvector(pB, bf16x4)); \
            short8v p8 = __builtin_shufflevector(pa, pb, 0, 1, 2, 3, 4, 5, 6, 7);      \
            pk[qi] = __builtin_bit_cast(bf16x8, p8);                                   \
        }                                                                              \
        setprio1();                                                                    \
        _Pragma("unroll")                                                              \
        for (int qi = 0; qi < QI_; qi++) {                                             \
            o2[qi][0] = __builtin_amdgcn_mfma_f32_16x16x32_bf16(CUR.va0, pk[qi], o2[qi][0], 0, 0, 0); \
            o2[qi][1] = __builtin_amdgcn_mfma_f32_16x16x32_bf16(CUR.va1, pk[qi], o2[qi][1], 0, 0, 0); \
            o2[qi][2] = __builtin_amdgcn_mfma_f32_16x16x32_bf16(CUR.va2, pk[qi], o2[qi][2], 0, 0, 0); \
            o2[qi][3] = __builtin_amdgcn_mfma_f32_16x16x32_bf16(CUR.va3, pk[qi], o2[qi][3], 0, 0, 0); \
            lacc[qi]  = __builtin_amdgcn_mfma_f32_16x16x32_bf16(ones8,   pk[qi], lacc[qi], 0, 0, 0); \
        }                                                                              \
        setprio0();                                                                    \
    }

    for (int t = 0; t < NT2_; t += 2) {
        ATTN_STEP(t,     fA, fB);
        ATTN_STEP(t + 1, fB, fA);
    }
#undef ATTN_STEP

    __syncthreads();   // all waves done with LDS K/V buffers before overlay

    // ---- epilogue: cross-wave reduction of O^T partials and denominators ----
    float* o_red0 = (float*)smem;            // [48 q][68 c]
    float* o_red1 = o_red0 + QT_*68;
    float* l_red  = o_red1 + QT_*68;         // [4][48]

    if (lane < 16) {
        #pragma unroll
        for (int qi = 0; qi < QI_; qi++) l_red[wave*QT_ + qi*16 + l16] = lacc[qi][0];
    }
    if (wave < 2) {
        float* od = (wave == 0) ? o_red0 : o_red1;
        #pragma unroll
        for (int qi = 0; qi < QI_; qi++)
            #pragma unroll
            for (int ct = 0; ct < 4; ct++)
                *(f32x4*)&od[(qi*16 + l16)*68 + ct*16 + quad*4] = o2[qi][ct];
    }
    __syncthreads();
    if (wave >= 2) {
        float* od = (wave == 2) ? o_red0 : o_red1;
        #pragma unroll
        for (int qi = 0; qi < QI_; qi++)
            #pragma unroll
            for (int ct = 0; ct < 4; ct++) {
                f32x4* p = (f32x4*)&od[(qi*16 + l16)*68 + ct*16 + quad*4];
                *p += o2[qi][ct];
            }
    }
    __syncthreads();
    if (tid < QT_) {
        float s = (l_red[tid] + l_red[QT_ + tid]) + (l_red[2*QT_ + tid] + l_red[3*QT_ + tid]);
        l_red[tid] = 1.f / s;
    }
    __syncthreads();

    float gmm = gamma_p[0];
    int c = tid >> 2, q4 = tid & 3;
    const float* xrow = x + ((size_t)b*C_ + c)*N_ + n_base;
    float* orow = out + ((size_t)b*C_ + c)*N_ + n_base;
    #pragma unroll
    for (int i = 0; i < QI_; i++) {
        int q0 = q4*4 + i*16;
        float4 xv = *(const float4*)(xrow + q0);
        float4 ov;
        float v0 = (o_red0[(q0+0)*68 + c] + o_red1[(q0+0)*68 + c]) * l_red[q0+0];
        float v1 = (o_red0[(q0+1)*68 + c] + o_red1[(q0+1)*68 + c]) * l_red[q0+1];
        float v2 = (o_red0[(q0+2)*68 + c] + o_red1[(q0+2)*68 + c]) * l_red[q0+2];
        float v3 = (o_red0[(q0+3)*68 + c] + o_red1[(q0+3)*68 + c]) * l_red[q0+3];
        ov.x = fmaf(gmm, v0, xv.x);
        ov.y = fmaf(gmm, v1, xv.y);
        ov.z = fmaf(gmm, v2, xv.z);
        ov.w = fmaf(gmm, v3, xv.w);
        *(float4*)(orow + q0) = ov;
    }
}

extern "C" void kernel_launch(void* const* d_in, const int* in_sizes, int n_in,
                              void* d_out, int out_size, void* d_ws, size_t ws_size,
                              hipStream_t stream) {
    const float* c2    = (const float*)d_in[0];
    const float* x     = (const float*)d_in[1];
    const float* w_ea1 = (const float*)d_in[2];
    const float* bn_w  = (const float*)d_in[3];
    const float* bn_b  = (const float*)d_in[4];
    const float* bn_m  = (const float*)d_in[5];
    const float* bn_v  = (const float*)d_in[6];
    const float* w_ea2 = (const float*)d_in[7];
    const float* b_ea2 = (const float*)d_in[8];
    const float* w_q   = (const float*)d_in[9];
    const float* b_q   = (const float*)d_in[10];
    const float* gamma = (const float*)d_in[11];
    float* out = (float*)d_out;

    char* ws = (char*)d_ws;
    float* ea            = (float*)(ws + 0);                // 36864 B
    unsigned short* kb   = (unsigned short*)(ws + 36864);   // 1179648 B
    unsigned short* vb   = (unsigned short*)(ws + 1216512); // 1179648 B

    prep_kernel<<<dim3((B_*M_)/32), dim3(256), 0, stream>>>(x, c2, w_q, b_q,
        w_ea1, bn_w, bn_b, bn_m, bn_v, w_ea2, b_ea2, kb, vb, ea);
    attn_kernel<<<dim3(B_*QB_), dim3(256), 0, stream>>>(w_q, b_q, kb, vb, ea, x, gamma, out);
}